// Round 1
// baseline (108145.239 us; speedup 1.0000x reference)
//
#include <hip/hip_runtime.h>
#include <math.h>

#define HD 1024
#define CD 256
#define TT 512
#define GD 4096                 // 4*H
#define NWG 256
#define NTH 1024
#define WPB (NTH/64)            // waves per block = 16
#define NWAVE (NWG*WPB)         // 4096
#define LAMF 0.05f

// ---------------- persistent device scratch (re-initialized every call) ----
__device__ float d_g1[GD], d_g2[GD], d_g3[GD];
__device__ float d_BU0[HD], d_BU1[HD], d_BU2[HD];
__device__ float d_z1[CD];
__device__ float d_h1[2][HD], d_c1[2][HD], d_h2[2][HD], d_c2[2][HD], d_h3[2][HD], d_c3[2][HD];
__device__ float d_rec1[2][CD], d_rec2[2][HD], d_rec3[2][HD];
__device__ float d_TD1[2][HD], d_TD2[2][HD];
__device__ int   d_bar;

__global__ void pc_init() { d_bar = 0; }

__device__ __forceinline__ float sigf(float x)     { return 1.f / (1.f + __expf(-x)); }
__device__ __forceinline__ float tanhfast(float x) { return 1.f - 2.f / (1.f + __expf(2.f * x)); }

// monotonic global barrier: all 256 WGs resident (grid==CU count), agent scope
__device__ __forceinline__ void gbar(int& target) {
  __syncthreads();
  if (threadIdx.x == 0) {
    __threadfence();            // flush WG writes to device-visible point (L2 wb)
    target += NWG;
    __hip_atomic_fetch_add(&d_bar, 1, __ATOMIC_ACQ_REL, __HIP_MEMORY_SCOPE_AGENT);
    while (__hip_atomic_load(&d_bar, __ATOMIC_ACQUIRE, __HIP_MEMORY_SCOPE_AGENT) < target)
      __builtin_amdgcn_s_sleep(8);
    __threadfence();            // invalidate caches before consuming others' data
  }
  __syncthreads();
}

__device__ __forceinline__ float wredsum(float v) {
  #pragma unroll
  for (int off = 32; off; off >>= 1) v += __shfl_xor(v, off);
  return v;
}

// block-wide reductions (used with all threads of a WG participating)
__device__ __forceinline__ float bredsum(float v, float* sred) {
  __syncthreads();
  v = wredsum(v);
  if ((threadIdx.x & 63) == 0) sred[threadIdx.x >> 6] = v;
  __syncthreads();
  float r = (threadIdx.x < WPB) ? sred[threadIdx.x] : 0.f;
  r += __shfl_xor(r, 1); r += __shfl_xor(r, 2); r += __shfl_xor(r, 4); r += __shfl_xor(r, 8);
  if (threadIdx.x == 0) sred[0] = r;
  __syncthreads();
  return sred[0];
}

__device__ __forceinline__ float bredmax(float v, float* sred) {
  __syncthreads();
  #pragma unroll
  for (int off = 32; off; off >>= 1) v = fmaxf(v, __shfl_xor(v, off));
  if ((threadIdx.x & 63) == 0) sred[threadIdx.x >> 6] = v;
  __syncthreads();
  float r = (threadIdx.x < WPB) ? sred[threadIdx.x] : -INFINITY;
  r = fmaxf(r, __shfl_xor(r, 1)); r = fmaxf(r, __shfl_xor(r, 2));
  r = fmaxf(r, __shfl_xor(r, 4)); r = fmaxf(r, __shfl_xor(r, 8));
  if (threadIdx.x == 0) sred[0] = r;
  __syncthreads();
  return sred[0];
}

// per-lane partial dot of one weight row against an LDS vector (n % 256 == 0)
__device__ __forceinline__ float dotp(const float* __restrict__ w, const float* xv, int n, int lane) {
  float a0 = 0.f, a1 = 0.f, a2 = 0.f, a3 = 0.f;
  for (int c = lane * 4; c < n; c += 256) {
    const float4 wv = *(const float4*)(w + c);
    const float4 vv = *(const float4*)(xv + c);
    a0 = fmaf(wv.x, vv.x, a0);
    a1 = fmaf(wv.y, vv.y, a1);
    a2 = fmaf(wv.z, vv.z, a2);
    a3 = fmaf(wv.w, vv.w, a3);
  }
  return (a0 + a1) + (a2 + a3);
}

__global__ __launch_bounds__(NTH, 1) void pc_main(
    const float* __restrict__ x,
    const float* __restrict__ Wih1, const float* __restrict__ Whh1,
    const float* __restrict__ bih1, const float* __restrict__ bhh1,
    const float* __restrict__ Vw1,  const float* __restrict__ Vb1,
    const float* __restrict__ Wih2, const float* __restrict__ Whh2,
    const float* __restrict__ bih2, const float* __restrict__ bhh2,
    const float* __restrict__ Vw2,  const float* __restrict__ Vb2,
    const float* __restrict__ Wih3, const float* __restrict__ Whh3,
    const float* __restrict__ bih3, const float* __restrict__ bhh3,
    const float* __restrict__ Vw3,  const float* __restrict__ Vb3,
    const float* __restrict__ Ww0,  const float* __restrict__ Wb0,
    const float* __restrict__ Ww1,  const float* __restrict__ Wb1,
    const float* __restrict__ Ww2,  const float* __restrict__ Wb2,
    const float* __restrict__ r1,   const float* __restrict__ r2,
    const float* __restrict__ r3,
    float* __restrict__ out) {
  const int tid  = threadIdx.x;
  const int lane = tid & 63;
  const int wid  = blockIdx.x * WPB + (tid >> 6);
  const bool iswg0 = (blockIdx.x == 0);

  __shared__ __align__(16) float s_x0[HD];
  __shared__ __align__(16) float s_x1[HD];
  __shared__ __align__(16) float s_x2[HD];
  __shared__ __align__(16) float s_aux[HD];
  __shared__ __align__(16) float s_small[CD];
  __shared__ float s_red[WPB];

  int bart = 0;
  float loss_acc = 0.f, fll_acc = 0.f;

  // ---------------- Stage P: init state + BU0(0) ----------------
  {
    float z = (tid < CD) ? r1[tid] : -INFINITY;
    float m = bredmax(z, s_red);
    float e = (tid < CD) ? __expf(z - m) : 0.f;
    float ssum = bredsum(e, s_red);
    if (tid < CD) {
      float p = e / ssum;               // rec1(0) = softmax(r1)
      s_small[tid] = x[tid] - p;        // TD0 at t=0
      if (iswg0) d_rec1[0][tid] = p;
    }
    if (iswg0) {
      for (int j = tid; j < HD; j += NTH) {
        d_h1[0][j] = 0.f; d_c1[0][j] = 0.f;
        d_h2[0][j] = 0.f; d_c2[0][j] = 0.f;
        d_h3[0][j] = 0.f; d_c3[0][j] = 0.f;
        d_TD1[0][j] = 0.f; d_TD2[0][j] = 0.f;
        d_rec2[0][j] = r2[j]; d_rec3[0][j] = r3[j];
      }
    }
    __syncthreads();
    for (int job = wid; job < HD; job += NWAVE) {
      float s = dotp(Ww0 + (size_t)job * CD, s_small, CD, lane);
      s = wredsum(s);
      if (lane == 0) d_BU0[job] = s + Wb0[job];
    }
  }
  gbar(bart);

  for (int t = 0; t < TT; ++t) {
    const int cur = t & 1, nxt = cur ^ 1;

    // ---- S1: g1 = Wih1@[BU0;TD1] + Whh1@h1 ; rec3 = Vw3@h3n (t>0) ----
    {
      for (int j = tid; j < HD; j += NTH) {
        s_x0[j] = d_BU0[j];
        s_x1[j] = d_TD1[cur][j];
        s_x2[j] = d_h1[cur][j];
      }
      if (t > 0) {
        const int prv = cur ^ 1;        // (t-1)&1
        for (int j = tid; j < HD; j += NTH) {
          float gi = d_g3[j], gf = d_g3[j + HD], gg = d_g3[j + 2 * HD], go = d_g3[j + 3 * HD];
          float c3n = sigf(gf) * d_c3[prv][j] + sigf(gi) * tanhfast(gg);
          float h3n = sigf(go) * tanhfast(c3n);
          s_aux[j] = h3n;
          if (iswg0) { d_h3[cur][j] = h3n; d_c3[cur][j] = c3n; }
        }
      }
      __syncthreads();
      const int njob = (t > 0) ? GD + HD : GD;
      for (int job = wid; job < njob; job += NWAVE) {
        if (job < GD) {
          const float* wr = Wih1 + (size_t)job * (2 * HD);
          float s = dotp(wr, s_x0, HD, lane)
                  + dotp(wr + HD, s_x1, HD, lane)
                  + dotp(Whh1 + (size_t)job * HD, s_x2, HD, lane);
          s = wredsum(s);
          if (lane == 0) d_g1[job] = s + bih1[job] + bhh1[job];
        } else {
          int rr = job - GD;
          float s = dotp(Vw3 + (size_t)rr * HD, s_aux, HD, lane);
          s = wredsum(s);
          if (lane == 0) d_rec3[cur][rr] = s + Vb3[rr];
        }
      }
    }
    gbar(bart);

    // ---- S2: lstm1 cell ; BU1 = Ww1@TD1n ; z1 = Vw1@h1n ----
    {
      float absum = 0.f;
      for (int j = tid; j < HD; j += NTH) {
        float gi = d_g1[j], gf = d_g1[j + HD], gg = d_g1[j + 2 * HD], go = d_g1[j + 3 * HD];
        float c1n = sigf(gf) * d_c1[cur][j] + sigf(gi) * tanhfast(gg);
        float h1n = sigf(go) * tanhfast(c1n);
        float td  = h1n - d_rec2[cur][j];
        s_x0[j] = h1n; s_x1[j] = td;
        if (iswg0) { d_h1[nxt][j] = h1n; d_c1[nxt][j] = c1n; d_TD1[nxt][j] = td; }
        absum += fabsf(td);
      }
      if (iswg0) {
        float tot = bredsum(absum, s_red);
        if (tid == 0) loss_acc += LAMF * tot;
      }
      __syncthreads();
      for (int job = wid; job < HD + CD; job += NWAVE) {
        if (job < HD) {
          float s = dotp(Ww1 + (size_t)job * HD, s_x1, HD, lane);
          s = wredsum(s);
          if (lane == 0) d_BU1[job] = s + Wb1[job];
        } else {
          int rr = job - HD;
          float s = dotp(Vw1 + (size_t)rr * HD, s_x0, HD, lane);
          s = wredsum(s);
          if (lane == 0) d_z1[rr] = s + Vb1[rr];
        }
      }
    }
    gbar(bart);

    // ---- S3: loss0 + softmax(z1) + predictions ; g2 matvec ----
    {
      for (int j = tid; j < HD; j += NTH) {
        s_x0[j] = d_BU1[j];
        s_x1[j] = d_TD2[cur][j];
        s_x2[j] = d_h2[cur][j];
      }
      if (iswg0) {
        float u = 0.f;
        if (tid < CD) {
          float p  = d_rec1[cur][tid];                // OLD rec1 (for step t)
          float xv = x[(size_t)t * CD + tid];
          u = xv * logf(p) + (1.f - xv) * logf(1.f - p);
        }
        float tot = bredsum(u, s_red);
        if (tid == 0) { loss_acc += -tot; fll_acc += -tot; }
        float z = (tid < CD) ? d_z1[tid] : -INFINITY;
        float m = bredmax(z, s_red);
        float e = (tid < CD) ? __expf(z - m) : 0.f;
        float ssum = bredsum(e, s_red);
        if (tid < CD) {
          float p = e / ssum;
          d_rec1[nxt][tid] = p;                       // rec1 for step t+1
          out[2 + (size_t)t * CD + tid] = p;          // predictions[t]
        }
      }
      __syncthreads();
      for (int job = wid; job < GD; job += NWAVE) {
        const float* wr = Wih2 + (size_t)job * (2 * HD);
        float s = dotp(wr, s_x0, HD, lane)
                + dotp(wr + HD, s_x1, HD, lane)
                + dotp(Whh2 + (size_t)job * HD, s_x2, HD, lane);
        s = wredsum(s);
        if (lane == 0) d_g2[job] = s + bih2[job] + bhh2[job];
      }
    }
    gbar(bart);

    // ---- S4: lstm2 cell ; BU2 = Ww2@TD2n ; rec2n = Vw2@h2n ----
    {
      float absum = 0.f;
      for (int j = tid; j < HD; j += NTH) {
        float gi = d_g2[j], gf = d_g2[j + HD], gg = d_g2[j + 2 * HD], go = d_g2[j + 3 * HD];
        float c2n = sigf(gf) * d_c2[cur][j] + sigf(gi) * tanhfast(gg);
        float h2n = sigf(go) * tanhfast(c2n);
        float td  = h2n - d_rec3[cur][j];
        s_x0[j] = h2n; s_x1[j] = td;
        if (iswg0) { d_h2[nxt][j] = h2n; d_c2[nxt][j] = c2n; d_TD2[nxt][j] = td; }
        absum += fabsf(td);
      }
      if (iswg0) {
        float tot = bredsum(absum, s_red);
        if (tid == 0) loss_acc += (LAMF * LAMF) * tot;
      }
      __syncthreads();
      for (int job = wid; job < 2 * HD; job += NWAVE) {
        if (job < HD) {
          float s = dotp(Ww2 + (size_t)job * HD, s_x1, HD, lane);
          s = wredsum(s);
          if (lane == 0) d_BU2[job] = s + Wb2[job];
        } else {
          int rr = job - HD;
          float s = dotp(Vw2 + (size_t)rr * HD, s_x0, HD, lane);
          s = wredsum(s);
          if (lane == 0) d_rec2[nxt][rr] = s + Vb2[rr];
        }
      }
    }
    gbar(bart);

    // ---- S5: g3 = Wih3@BU2 + Whh3@h3 ; BU0(t+1) = Ww0@(x[t+1]-rec1n) ----
    {
      for (int j = tid; j < HD; j += NTH) {
        s_x0[j] = d_BU2[j];
        s_x2[j] = d_h3[cur][j];
      }
      if (t < TT - 1 && tid < CD)
        s_small[tid] = x[(size_t)(t + 1) * CD + tid] - d_rec1[nxt][tid];
      __syncthreads();
      const int njob = (t < TT - 1) ? GD + HD : GD;
      for (int job = wid; job < njob; job += NWAVE) {
        if (job < GD) {
          float s = dotp(Wih3 + (size_t)job * HD, s_x0, HD, lane)
                  + dotp(Whh3 + (size_t)job * HD, s_x2, HD, lane);
          s = wredsum(s);
          if (lane == 0) d_g3[job] = s + bih3[job] + bhh3[job];
        } else {
          int rr = job - GD;
          float s = dotp(Ww0 + (size_t)rr * CD, s_small, CD, lane);
          s = wredsum(s);
          if (lane == 0) d_BU0[rr] = s + Wb0[rr];
        }
      }
    }
    gbar(bart);
  }

  if (iswg0 && tid == 0) { out[0] = loss_acc; out[1] = fll_acc; }
}

extern "C" void kernel_launch(void* const* d_in, const int* in_sizes, int n_in,
                              void* d_out, int out_size, void* d_ws, size_t ws_size,
                              hipStream_t stream) {
  const float* x    = (const float*)d_in[0];
  const float* Wih1 = (const float*)d_in[1];
  const float* Whh1 = (const float*)d_in[2];
  const float* bih1 = (const float*)d_in[3];
  const float* bhh1 = (const float*)d_in[4];
  const float* Vw1  = (const float*)d_in[5];
  const float* Vb1  = (const float*)d_in[6];
  const float* Wih2 = (const float*)d_in[7];
  const float* Whh2 = (const float*)d_in[8];
  const float* bih2 = (const float*)d_in[9];
  const float* bhh2 = (const float*)d_in[10];
  const float* Vw2  = (const float*)d_in[11];
  const float* Vb2  = (const float*)d_in[12];
  const float* Wih3 = (const float*)d_in[13];
  const float* Whh3 = (const float*)d_in[14];
  const float* bih3 = (const float*)d_in[15];
  const float* bhh3 = (const float*)d_in[16];
  const float* Vw3  = (const float*)d_in[17];
  const float* Vb3  = (const float*)d_in[18];
  const float* Ww0  = (const float*)d_in[19];
  const float* Wb0  = (const float*)d_in[20];
  const float* Ww1  = (const float*)d_in[21];
  const float* Wb1  = (const float*)d_in[22];
  const float* Ww2  = (const float*)d_in[23];
  const float* Wb2  = (const float*)d_in[24];
  const float* r1   = (const float*)d_in[25];
  const float* r2   = (const float*)d_in[26];
  const float* r3   = (const float*)d_in[27];

  pc_init<<<1, 1, 0, stream>>>();
  pc_main<<<NWG, NTH, 0, stream>>>(x, Wih1, Whh1, bih1, bhh1, Vw1, Vb1,
                                   Wih2, Whh2, bih2, bhh2, Vw2, Vb2,
                                   Wih3, Whh3, bih3, bhh3, Vw3, Vb3,
                                   Ww0, Wb0, Ww1, Wb1, Ww2, Wb2,
                                   r1, r2, r3, (float*)d_out);
}

// Round 2
// 54139.429 us; speedup vs baseline: 1.9975x; 1.9975x over previous
//
#include <hip/hip_runtime.h>
#include <math.h>

#define HD 1024
#define CD 256
#define TT 512
#define GD 4096                 // 4*H
#define NWG 256
#define NTH 1024
#define WPB (NTH/64)            // waves per block = 16
#define NWAVE (NWG*WPB)         // 4096
#define LAMF 0.05f

// ---------------- persistent device scratch (re-initialized every call) ----
__device__ float d_g1[GD], d_g2[GD], d_g3[GD];
__device__ float d_BU0[HD], d_BU1[HD], d_BU2[HD];
__device__ float d_z1[CD];
__device__ float d_h1[2][HD], d_c1[2][HD], d_h2[2][HD], d_c2[2][HD], d_h3[2][HD], d_c3[2][HD];
__device__ float d_rec1[2][CD], d_rec2[2][HD], d_rec3[2][HD];
__device__ float d_TD1[2][HD], d_TD2[2][HD];
__device__ int   d_bar;

__global__ void pc_init() { d_bar = 0; }

__device__ __forceinline__ float sigf(float x)     { return 1.f / (1.f + __expf(-x)); }
__device__ __forceinline__ float tanhfast(float x) { return 1.f - 2.f / (1.f + __expf(2.f * x)); }

// Coherent (L1/L2-bypassing, sc0+sc1) access for cross-WG activation data.
// Using these for ALL inter-workgroup values means NO cache-invalidating
// fence is needed at the barrier -> read-only weights stay hot in L1/L2.
__device__ __forceinline__ float cload(const float* p) {
  return __hip_atomic_load(p, __ATOMIC_RELAXED, __HIP_MEMORY_SCOPE_AGENT);
}
__device__ __forceinline__ void cstore(float* p, float v) {
  __hip_atomic_store(p, v, __ATOMIC_RELAXED, __HIP_MEMORY_SCOPE_AGENT);
}

// monotonic global barrier: all 256 WGs resident (grid==CU count).
// RELEASE on the signal orders the preceding sc0/sc1 write-through stores
// (emits vmcnt wait + wbl2 writeback; clean weight lines stay valid).
// Poll is RELAXED (no buffer_inv!). Data reads are themselves coherent.
__device__ __forceinline__ void gbar(int& target) {
  __syncthreads();
  if (threadIdx.x == 0) {
    target += NWG;
    __hip_atomic_fetch_add(&d_bar, 1, __ATOMIC_RELEASE, __HIP_MEMORY_SCOPE_AGENT);
    while (__hip_atomic_load(&d_bar, __ATOMIC_RELAXED, __HIP_MEMORY_SCOPE_AGENT) < target)
      __builtin_amdgcn_s_sleep(1);
  }
  __syncthreads();
}

__device__ __forceinline__ float wredsum(float v) {
  #pragma unroll
  for (int off = 32; off; off >>= 1) v += __shfl_xor(v, off);
  return v;
}

// block-wide reductions (used with all threads of a WG participating)
__device__ __forceinline__ float bredsum(float v, float* sred) {
  __syncthreads();
  v = wredsum(v);
  if ((threadIdx.x & 63) == 0) sred[threadIdx.x >> 6] = v;
  __syncthreads();
  float r = (threadIdx.x < WPB) ? sred[threadIdx.x] : 0.f;
  r += __shfl_xor(r, 1); r += __shfl_xor(r, 2); r += __shfl_xor(r, 4); r += __shfl_xor(r, 8);
  if (threadIdx.x == 0) sred[0] = r;
  __syncthreads();
  return sred[0];
}

__device__ __forceinline__ float bredmax(float v, float* sred) {
  __syncthreads();
  #pragma unroll
  for (int off = 32; off; off >>= 1) v = fmaxf(v, __shfl_xor(v, off));
  if ((threadIdx.x & 63) == 0) sred[threadIdx.x >> 6] = v;
  __syncthreads();
  float r = (threadIdx.x < WPB) ? sred[threadIdx.x] : -INFINITY;
  r = fmaxf(r, __shfl_xor(r, 1)); r = fmaxf(r, __shfl_xor(r, 2));
  r = fmaxf(r, __shfl_xor(r, 4)); r = fmaxf(r, __shfl_xor(r, 8));
  if (threadIdx.x == 0) sred[0] = r;
  __syncthreads();
  return sred[0];
}

// per-lane partial dot of one weight row against an LDS vector (n % 256 == 0)
__device__ __forceinline__ float dotp(const float* __restrict__ w, const float* xv, int n, int lane) {
  float a0 = 0.f, a1 = 0.f, a2 = 0.f, a3 = 0.f;
  for (int c = lane * 4; c < n; c += 256) {
    const float4 wv = *(const float4*)(w + c);
    const float4 vv = *(const float4*)(xv + c);
    a0 = fmaf(wv.x, vv.x, a0);
    a1 = fmaf(wv.y, vv.y, a1);
    a2 = fmaf(wv.z, vv.z, a2);
    a3 = fmaf(wv.w, vv.w, a3);
  }
  return (a0 + a1) + (a2 + a3);
}

__global__ __launch_bounds__(NTH, 1) void pc_main(
    const float* __restrict__ x,
    const float* __restrict__ Wih1, const float* __restrict__ Whh1,
    const float* __restrict__ bih1, const float* __restrict__ bhh1,
    const float* __restrict__ Vw1,  const float* __restrict__ Vb1,
    const float* __restrict__ Wih2, const float* __restrict__ Whh2,
    const float* __restrict__ bih2, const float* __restrict__ bhh2,
    const float* __restrict__ Vw2,  const float* __restrict__ Vb2,
    const float* __restrict__ Wih3, const float* __restrict__ Whh3,
    const float* __restrict__ bih3, const float* __restrict__ bhh3,
    const float* __restrict__ Vw3,  const float* __restrict__ Vb3,
    const float* __restrict__ Ww0,  const float* __restrict__ Wb0,
    const float* __restrict__ Ww1,  const float* __restrict__ Wb1,
    const float* __restrict__ Ww2,  const float* __restrict__ Wb2,
    const float* __restrict__ r1,   const float* __restrict__ r2,
    const float* __restrict__ r3,
    float* __restrict__ out) {
  const int tid  = threadIdx.x;
  const int lane = tid & 63;
  const int wid  = blockIdx.x * WPB + (tid >> 6);
  const bool iswg0 = (blockIdx.x == 0);

  __shared__ __align__(16) float s_x0[HD];
  __shared__ __align__(16) float s_x1[HD];
  __shared__ __align__(16) float s_x2[HD];
  __shared__ __align__(16) float s_aux[HD];
  __shared__ __align__(16) float s_small[CD];
  __shared__ float s_red[WPB];

  int bart = 0;
  float loss_acc = 0.f, fll_acc = 0.f;

  // ---------------- Stage P: init state + BU0(0) ----------------
  {
    float z = (tid < CD) ? r1[tid] : -INFINITY;
    float m = bredmax(z, s_red);
    float e = (tid < CD) ? __expf(z - m) : 0.f;
    float ssum = bredsum(e, s_red);
    if (tid < CD) {
      float p = e / ssum;               // rec1(0) = softmax(r1)
      s_small[tid] = x[tid] - p;        // TD0 at t=0
      if (iswg0) cstore(&d_rec1[0][tid], p);
    }
    if (iswg0) {
      for (int j = tid; j < HD; j += NTH) {
        cstore(&d_h1[0][j], 0.f); cstore(&d_c1[0][j], 0.f);
        cstore(&d_h2[0][j], 0.f); cstore(&d_c2[0][j], 0.f);
        cstore(&d_h3[0][j], 0.f); cstore(&d_c3[0][j], 0.f);
        cstore(&d_TD1[0][j], 0.f); cstore(&d_TD2[0][j], 0.f);
        cstore(&d_rec2[0][j], r2[j]); cstore(&d_rec3[0][j], r3[j]);
      }
    }
    __syncthreads();
    for (int job = wid; job < HD; job += NWAVE) {
      float s = dotp(Ww0 + (size_t)job * CD, s_small, CD, lane);
      s = wredsum(s);
      if (lane == 0) cstore(&d_BU0[job], s + Wb0[job]);
    }
  }
  gbar(bart);

  for (int t = 0; t < TT; ++t) {
    const int cur = t & 1, nxt = cur ^ 1;

    // ---- S1: g1 = Wih1@[BU0;TD1] + Whh1@h1 ; rec3 = Vw3@h3n (t>0) ----
    {
      for (int j = tid; j < HD; j += NTH) {
        s_x0[j] = cload(&d_BU0[j]);
        s_x1[j] = cload(&d_TD1[cur][j]);
        s_x2[j] = cload(&d_h1[cur][j]);
      }
      if (t > 0) {
        const int prv = cur ^ 1;        // (t-1)&1
        for (int j = tid; j < HD; j += NTH) {
          float gi = cload(&d_g3[j]), gf = cload(&d_g3[j + HD]);
          float gg = cload(&d_g3[j + 2 * HD]), go = cload(&d_g3[j + 3 * HD]);
          float c3n = sigf(gf) * cload(&d_c3[prv][j]) + sigf(gi) * tanhfast(gg);
          float h3n = sigf(go) * tanhfast(c3n);
          s_aux[j] = h3n;
          if (iswg0) { cstore(&d_h3[cur][j], h3n); cstore(&d_c3[cur][j], c3n); }
        }
      }
      __syncthreads();
      const int njob = (t > 0) ? GD + HD : GD;
      for (int job = wid; job < njob; job += NWAVE) {
        if (job < GD) {
          const float* wr = Wih1 + (size_t)job * (2 * HD);
          float s = dotp(wr, s_x0, HD, lane)
                  + dotp(wr + HD, s_x1, HD, lane)
                  + dotp(Whh1 + (size_t)job * HD, s_x2, HD, lane);
          s = wredsum(s);
          if (lane == 0) cstore(&d_g1[job], s + bih1[job] + bhh1[job]);
        } else {
          int rr = job - GD;
          float s = dotp(Vw3 + (size_t)rr * HD, s_aux, HD, lane);
          s = wredsum(s);
          if (lane == 0) cstore(&d_rec3[cur][rr], s + Vb3[rr]);
        }
      }
    }
    gbar(bart);

    // ---- S2: lstm1 cell ; BU1 = Ww1@TD1n ; z1 = Vw1@h1n ----
    {
      float absum = 0.f;
      for (int j = tid; j < HD; j += NTH) {
        float gi = cload(&d_g1[j]), gf = cload(&d_g1[j + HD]);
        float gg = cload(&d_g1[j + 2 * HD]), go = cload(&d_g1[j + 3 * HD]);
        float c1n = sigf(gf) * cload(&d_c1[cur][j]) + sigf(gi) * tanhfast(gg);
        float h1n = sigf(go) * tanhfast(c1n);
        float td  = h1n - cload(&d_rec2[cur][j]);
        s_x0[j] = h1n; s_x1[j] = td;
        if (iswg0) { cstore(&d_h1[nxt][j], h1n); cstore(&d_c1[nxt][j], c1n); cstore(&d_TD1[nxt][j], td); }
        absum += fabsf(td);
      }
      if (iswg0) {
        float tot = bredsum(absum, s_red);
        if (tid == 0) loss_acc += LAMF * tot;
      }
      __syncthreads();
      for (int job = wid; job < HD + CD; job += NWAVE) {
        if (job < HD) {
          float s = dotp(Ww1 + (size_t)job * HD, s_x1, HD, lane);
          s = wredsum(s);
          if (lane == 0) cstore(&d_BU1[job], s + Wb1[job]);
        } else {
          int rr = job - HD;
          float s = dotp(Vw1 + (size_t)rr * HD, s_x0, HD, lane);
          s = wredsum(s);
          if (lane == 0) cstore(&d_z1[rr], s + Vb1[rr]);
        }
      }
    }
    gbar(bart);

    // ---- S3: loss0 + softmax(z1) + predictions ; g2 matvec ----
    {
      for (int j = tid; j < HD; j += NTH) {
        s_x0[j] = cload(&d_BU1[j]);
        s_x1[j] = cload(&d_TD2[cur][j]);
        s_x2[j] = cload(&d_h2[cur][j]);
      }
      if (iswg0) {
        float u = 0.f;
        if (tid < CD) {
          float p  = cload(&d_rec1[cur][tid]);        // OLD rec1 (for step t)
          float xv = x[(size_t)t * CD + tid];
          u = xv * logf(p) + (1.f - xv) * logf(1.f - p);
        }
        float tot = bredsum(u, s_red);
        if (tid == 0) { loss_acc += -tot; fll_acc += -tot; }
        float z = (tid < CD) ? cload(&d_z1[tid]) : -INFINITY;
        float m = bredmax(z, s_red);
        float e = (tid < CD) ? __expf(z - m) : 0.f;
        float ssum = bredsum(e, s_red);
        if (tid < CD) {
          float p = e / ssum;
          cstore(&d_rec1[nxt][tid], p);               // rec1 for step t+1
          out[2 + (size_t)t * CD + tid] = p;          // predictions[t]
        }
      }
      __syncthreads();
      for (int job = wid; job < GD; job += NWAVE) {
        const float* wr = Wih2 + (size_t)job * (2 * HD);
        float s = dotp(wr, s_x0, HD, lane)
                + dotp(wr + HD, s_x1, HD, lane)
                + dotp(Whh2 + (size_t)job * HD, s_x2, HD, lane);
        s = wredsum(s);
        if (lane == 0) cstore(&d_g2[job], s + bih2[job] + bhh2[job]);
      }
    }
    gbar(bart);

    // ---- S4: lstm2 cell ; BU2 = Ww2@TD2n ; rec2n = Vw2@h2n ----
    {
      float absum = 0.f;
      for (int j = tid; j < HD; j += NTH) {
        float gi = cload(&d_g2[j]), gf = cload(&d_g2[j + HD]);
        float gg = cload(&d_g2[j + 2 * HD]), go = cload(&d_g2[j + 3 * HD]);
        float c2n = sigf(gf) * cload(&d_c2[cur][j]) + sigf(gi) * tanhfast(gg);
        float h2n = sigf(go) * tanhfast(c2n);
        float td  = h2n - cload(&d_rec3[cur][j]);
        s_x0[j] = h2n; s_x1[j] = td;
        if (iswg0) { cstore(&d_h2[nxt][j], h2n); cstore(&d_c2[nxt][j], c2n); cstore(&d_TD2[nxt][j], td); }
        absum += fabsf(td);
      }
      if (iswg0) {
        float tot = bredsum(absum, s_red);
        if (tid == 0) loss_acc += (LAMF * LAMF) * tot;
      }
      __syncthreads();
      for (int job = wid; job < 2 * HD; job += NWAVE) {
        if (job < HD) {
          float s = dotp(Ww2 + (size_t)job * HD, s_x1, HD, lane);
          s = wredsum(s);
          if (lane == 0) cstore(&d_BU2[job], s + Wb2[job]);
        } else {
          int rr = job - HD;
          float s = dotp(Vw2 + (size_t)rr * HD, s_x0, HD, lane);
          s = wredsum(s);
          if (lane == 0) cstore(&d_rec2[nxt][rr], s + Vb2[rr]);
        }
      }
    }
    gbar(bart);

    // ---- S5: g3 = Wih3@BU2 + Whh3@h3 ; BU0(t+1) = Ww0@(x[t+1]-rec1n) ----
    {
      for (int j = tid; j < HD; j += NTH) {
        s_x0[j] = cload(&d_BU2[j]);
        s_x2[j] = cload(&d_h3[cur][j]);
      }
      if (t < TT - 1 && tid < CD)
        s_small[tid] = x[(size_t)(t + 1) * CD + tid] - cload(&d_rec1[nxt][tid]);
      __syncthreads();
      const int njob = (t < TT - 1) ? GD + HD : GD;
      for (int job = wid; job < njob; job += NWAVE) {
        if (job < GD) {
          float s = dotp(Wih3 + (size_t)job * HD, s_x0, HD, lane)
                  + dotp(Whh3 + (size_t)job * HD, s_x2, HD, lane);
          s = wredsum(s);
          if (lane == 0) cstore(&d_g3[job], s + bih3[job] + bhh3[job]);
        } else {
          int rr = job - GD;
          float s = dotp(Ww0 + (size_t)rr * CD, s_small, CD, lane);
          s = wredsum(s);
          if (lane == 0) cstore(&d_BU0[rr], s + Wb0[rr]);
        }
      }
    }
    gbar(bart);
  }

  if (iswg0 && tid == 0) { out[0] = loss_acc; out[1] = fll_acc; }
}

extern "C" void kernel_launch(void* const* d_in, const int* in_sizes, int n_in,
                              void* d_out, int out_size, void* d_ws, size_t ws_size,
                              hipStream_t stream) {
  const float* x    = (const float*)d_in[0];
  const float* Wih1 = (const float*)d_in[1];
  const float* Whh1 = (const float*)d_in[2];
  const float* bih1 = (const float*)d_in[3];
  const float* bhh1 = (const float*)d_in[4];
  const float* Vw1  = (const float*)d_in[5];
  const float* Vb1  = (const float*)d_in[6];
  const float* Wih2 = (const float*)d_in[7];
  const float* Whh2 = (const float*)d_in[8];
  const float* bih2 = (const float*)d_in[9];
  const float* bhh2 = (const float*)d_in[10];
  const float* Vw2  = (const float*)d_in[11];
  const float* Vb2  = (const float*)d_in[12];
  const float* Wih3 = (const float*)d_in[13];
  const float* Whh3 = (const float*)d_in[14];
  const float* bih3 = (const float*)d_in[15];
  const float* bhh3 = (const float*)d_in[16];
  const float* Vw3  = (const float*)d_in[17];
  const float* Vb3  = (const float*)d_in[18];
  const float* Ww0  = (const float*)d_in[19];
  const float* Wb0  = (const float*)d_in[20];
  const float* Ww1  = (const float*)d_in[21];
  const float* Wb1  = (const float*)d_in[22];
  const float* Ww2  = (const float*)d_in[23];
  const float* Wb2  = (const float*)d_in[24];
  const float* r1   = (const float*)d_in[25];
  const float* r2   = (const float*)d_in[26];
  const float* r3   = (const float*)d_in[27];

  pc_init<<<1, 1, 0, stream>>>();
  pc_main<<<NWG, NTH, 0, stream>>>(x, Wih1, Whh1, bih1, bhh1, Vw1, Vb1,
                                   Wih2, Whh2, bih2, bhh2, Vw2, Vb2,
                                   Wih3, Whh3, bih3, bhh3, Vw3, Vb3,
                                   Ww0, Wb0, Ww1, Wb1, Ww2, Wb2,
                                   r1, r2, r3, (float*)d_out);
}

// Round 3
// 35322.305 us; speedup vs baseline: 3.0617x; 1.5327x over previous
//
#include <hip/hip_runtime.h>
#include <math.h>

#define HD 1024
#define CD 256
#define TT 512
#define GD 4096                 // 4*H
#define NWG 256
#define NTH 1024
#define WPB (NTH/64)            // waves per block = 16
#define NWAVE (NWG*WPB)         // 4096
#define LAMF 0.05f

// ---------------- persistent device scratch (re-initialized every call) ----
__device__ float d_g1[GD], d_g2[GD], d_g3[GD];
__device__ float d_BU0[HD], d_BU1[HD], d_BU2[HD];
__device__ float d_z1[CD];
__device__ float d_h1[2][HD], d_c1[2][HD], d_h2[2][HD], d_c2[2][HD], d_h3[2][HD], d_c3[2][HD];
__device__ float d_rec1[2][CD], d_rec2[2][HD], d_rec3[2][HD];
__device__ float d_TD1[2][HD], d_TD2[2][HD];
// distributed barrier state: one padded flag line per WG + one release line
__device__ int d_arr[NWG][32];
__device__ int d_rel;

__global__ void pc_init() { d_arr[threadIdx.x][0] = 0; if (threadIdx.x == 0) d_rel = 0; }

__device__ __forceinline__ float sigf(float x)     { return 1.f / (1.f + __expf(-x)); }
__device__ __forceinline__ float tanhfast(float x) { return 1.f - 2.f / (1.f + __expf(2.f * x)); }

// Coherent (L1/L2-bypassing) access for cross-WG activation data.
// All inter-WG values go through these -> no cache-invalidating fence needed
// anywhere -> read-only weights stay hot in L1/L2 across all 2561 barriers.
__device__ __forceinline__ float cload(const float* p) {
  return __hip_atomic_load(p, __ATOMIC_RELAXED, __HIP_MEMORY_SCOPE_AGENT);
}
__device__ __forceinline__ void cstore(float* p, float v) {
  __hip_atomic_store(p, v, __ATOMIC_RELAXED, __HIP_MEMORY_SCOPE_AGENT);
}

// Distributed epoch barrier (all NWG WGs resident; grid == CU count).
// Arrival: each WG release-stores its epoch to its OWN cache line (parallel,
// no RMW serialization). WG0 lanes 1..255 each poll one flag; then WG0
// release-stores d_rel; other WGs poll d_rel. RELEASE = vmcnt-drain of the
// producer's sc0/sc1 data stores; polls are RELAXED (no buffer_inv).
__device__ __forceinline__ void gbar(int& ep) {
  ++ep;
  __syncthreads();
  const int tid = threadIdx.x;
  if (blockIdx.x == 0) {
    if (tid >= 1 && tid < NWG) {
      while (__hip_atomic_load(&d_arr[tid][0], __ATOMIC_RELAXED, __HIP_MEMORY_SCOPE_AGENT) < ep)
        __builtin_amdgcn_s_sleep(1);
    }
    __syncthreads();
    if (tid == 0)
      __hip_atomic_store(&d_rel, ep, __ATOMIC_RELEASE, __HIP_MEMORY_SCOPE_AGENT);
  } else {
    if (tid == 0) {
      __hip_atomic_store(&d_arr[blockIdx.x][0], ep, __ATOMIC_RELEASE, __HIP_MEMORY_SCOPE_AGENT);
      while (__hip_atomic_load(&d_rel, __ATOMIC_RELAXED, __HIP_MEMORY_SCOPE_AGENT) < ep)
        __builtin_amdgcn_s_sleep(1);
    }
    __syncthreads();
  }
}

__device__ __forceinline__ float wredsum(float v) {
  #pragma unroll
  for (int off = 32; off; off >>= 1) v += __shfl_xor(v, off);
  return v;
}

// block-wide reductions (used with all threads of a WG participating)
__device__ __forceinline__ float bredsum(float v, float* sred) {
  __syncthreads();
  v = wredsum(v);
  if ((threadIdx.x & 63) == 0) sred[threadIdx.x >> 6] = v;
  __syncthreads();
  float r = (threadIdx.x < WPB) ? sred[threadIdx.x] : 0.f;
  r += __shfl_xor(r, 1); r += __shfl_xor(r, 2); r += __shfl_xor(r, 4); r += __shfl_xor(r, 8);
  if (threadIdx.x == 0) sred[0] = r;
  __syncthreads();
  return sred[0];
}

__device__ __forceinline__ float bredmax(float v, float* sred) {
  __syncthreads();
  #pragma unroll
  for (int off = 32; off; off >>= 1) v = fmaxf(v, __shfl_xor(v, off));
  if ((threadIdx.x & 63) == 0) sred[threadIdx.x >> 6] = v;
  __syncthreads();
  float r = (threadIdx.x < WPB) ? sred[threadIdx.x] : -INFINITY;
  r = fmaxf(r, __shfl_xor(r, 1)); r = fmaxf(r, __shfl_xor(r, 2));
  r = fmaxf(r, __shfl_xor(r, 4)); r = fmaxf(r, __shfl_xor(r, 8));
  if (threadIdx.x == 0) sred[0] = r;
  __syncthreads();
  return sred[0];
}

// per-lane partial dot of one weight row against an LDS vector (n % 256 == 0)
__device__ __forceinline__ float dotp(const float* __restrict__ w, const float* xv, int n, int lane) {
  float a0 = 0.f, a1 = 0.f, a2 = 0.f, a3 = 0.f;
  for (int c = lane * 4; c < n; c += 256) {
    const float4 wv = *(const float4*)(w + c);
    const float4 vv = *(const float4*)(xv + c);
    a0 = fmaf(wv.x, vv.x, a0);
    a1 = fmaf(wv.y, vv.y, a1);
    a2 = fmaf(wv.z, vv.z, a2);
    a3 = fmaf(wv.w, vv.w, a3);
  }
  return (a0 + a1) + (a2 + a3);
}

__global__ __launch_bounds__(NTH, 1) void pc_main(
    const float* __restrict__ x,
    const float* __restrict__ Wih1, const float* __restrict__ Whh1,
    const float* __restrict__ bih1, const float* __restrict__ bhh1,
    const float* __restrict__ Vw1,  const float* __restrict__ Vb1,
    const float* __restrict__ Wih2, const float* __restrict__ Whh2,
    const float* __restrict__ bih2, const float* __restrict__ bhh2,
    const float* __restrict__ Vw2,  const float* __restrict__ Vb2,
    const float* __restrict__ Wih3, const float* __restrict__ Whh3,
    const float* __restrict__ bih3, const float* __restrict__ bhh3,
    const float* __restrict__ Vw3,  const float* __restrict__ Vb3,
    const float* __restrict__ Ww0,  const float* __restrict__ Wb0,
    const float* __restrict__ Ww1,  const float* __restrict__ Wb1,
    const float* __restrict__ Ww2,  const float* __restrict__ Wb2,
    const float* __restrict__ r1,   const float* __restrict__ r2,
    const float* __restrict__ r3,
    float* __restrict__ out) {
  const int tid  = threadIdx.x;
  const int lane = tid & 63;
  const int wid  = blockIdx.x * WPB + (tid >> 6);
  const bool iswg0 = (blockIdx.x == 0);

  __shared__ __align__(16) float s_x0[HD];
  __shared__ __align__(16) float s_x1[HD];
  __shared__ __align__(16) float s_x2[HD];
  __shared__ __align__(16) float s_aux[HD];
  __shared__ __align__(16) float s_small[CD];
  __shared__ float s_red[WPB];

  int ep = 0;
  float loss_acc = 0.f, fll_acc = 0.f;

  // ---------------- Stage P: init state + BU0(0) ----------------
  {
    float z = (tid < CD) ? r1[tid] : -INFINITY;
    float m = bredmax(z, s_red);
    float e = (tid < CD) ? __expf(z - m) : 0.f;
    float ssum = bredsum(e, s_red);
    if (tid < CD) {
      float p = e / ssum;               // rec1(0) = softmax(r1)
      s_small[tid] = x[tid] - p;        // TD0 at t=0
      if (iswg0) cstore(&d_rec1[0][tid], p);
    }
    if (iswg0) {
      for (int j = tid; j < HD; j += NTH) {
        cstore(&d_h1[0][j], 0.f); cstore(&d_c1[0][j], 0.f);
        cstore(&d_h2[0][j], 0.f); cstore(&d_c2[0][j], 0.f);
        cstore(&d_h3[0][j], 0.f); cstore(&d_c3[0][j], 0.f);
        cstore(&d_TD1[0][j], 0.f); cstore(&d_TD2[0][j], 0.f);
        cstore(&d_rec2[0][j], r2[j]); cstore(&d_rec3[0][j], r3[j]);
      }
    }
    __syncthreads();
    for (int job = wid; job < HD; job += NWAVE) {
      float s = dotp(Ww0 + (size_t)job * CD, s_small, CD, lane);
      s = wredsum(s);
      if (lane == 0) cstore(&d_BU0[job], s + Wb0[job]);
    }
  }
  gbar(ep);

  for (int t = 0; t < TT; ++t) {
    const int cur = t & 1, nxt = cur ^ 1;

    // ---- S1: g1 = Wih1@[BU0;TD1] + Whh1@h1 ; rec3 = Vw3@h3n (t>0) ----
    {
      for (int j = tid; j < HD; j += NTH) {
        s_x0[j] = cload(&d_BU0[j]);
        s_x1[j] = cload(&d_TD1[cur][j]);
        s_x2[j] = cload(&d_h1[cur][j]);
      }
      if (t > 0) {
        const int prv = cur ^ 1;        // (t-1)&1
        for (int j = tid; j < HD; j += NTH) {
          float gi = cload(&d_g3[j]), gf = cload(&d_g3[j + HD]);
          float gg = cload(&d_g3[j + 2 * HD]), go = cload(&d_g3[j + 3 * HD]);
          float c3n = sigf(gf) * cload(&d_c3[prv][j]) + sigf(gi) * tanhfast(gg);
          float h3n = sigf(go) * tanhfast(c3n);
          s_aux[j] = h3n;
          if (iswg0) { cstore(&d_h3[cur][j], h3n); cstore(&d_c3[cur][j], c3n); }
        }
      }
      __syncthreads();
      const int njob = (t > 0) ? GD + HD : GD;
      for (int job = wid; job < njob; job += NWAVE) {
        if (job < GD) {
          const float* wr = Wih1 + (size_t)job * (2 * HD);
          float s = dotp(wr, s_x0, HD, lane)
                  + dotp(wr + HD, s_x1, HD, lane)
                  + dotp(Whh1 + (size_t)job * HD, s_x2, HD, lane);
          s = wredsum(s);
          if (lane == 0) cstore(&d_g1[job], s + bih1[job] + bhh1[job]);
        } else {
          int rr = job - GD;
          float s = dotp(Vw3 + (size_t)rr * HD, s_aux, HD, lane);
          s = wredsum(s);
          if (lane == 0) cstore(&d_rec3[cur][rr], s + Vb3[rr]);
        }
      }
    }
    gbar(ep);

    // ---- S2: lstm1 cell ; BU1 = Ww1@TD1n ; z1 = Vw1@h1n ----
    {
      float absum = 0.f;
      for (int j = tid; j < HD; j += NTH) {
        float gi = cload(&d_g1[j]), gf = cload(&d_g1[j + HD]);
        float gg = cload(&d_g1[j + 2 * HD]), go = cload(&d_g1[j + 3 * HD]);
        float c1n = sigf(gf) * cload(&d_c1[cur][j]) + sigf(gi) * tanhfast(gg);
        float h1n = sigf(go) * tanhfast(c1n);
        float td  = h1n - cload(&d_rec2[cur][j]);
        s_x0[j] = h1n; s_x1[j] = td;
        if (iswg0) { cstore(&d_h1[nxt][j], h1n); cstore(&d_c1[nxt][j], c1n); cstore(&d_TD1[nxt][j], td); }
        absum += fabsf(td);
      }
      if (iswg0) {
        float tot = bredsum(absum, s_red);
        if (tid == 0) loss_acc += LAMF * tot;
      }
      __syncthreads();
      for (int job = wid; job < HD + CD; job += NWAVE) {
        if (job < HD) {
          float s = dotp(Ww1 + (size_t)job * HD, s_x1, HD, lane);
          s = wredsum(s);
          if (lane == 0) cstore(&d_BU1[job], s + Wb1[job]);
        } else {
          int rr = job - HD;
          float s = dotp(Vw1 + (size_t)rr * HD, s_x0, HD, lane);
          s = wredsum(s);
          if (lane == 0) cstore(&d_z1[rr], s + Vb1[rr]);
        }
      }
    }
    gbar(ep);

    // ---- S3: loss0 + softmax(z1) + predictions ; g2 matvec ----
    {
      for (int j = tid; j < HD; j += NTH) {
        s_x0[j] = cload(&d_BU1[j]);
        s_x1[j] = cload(&d_TD2[cur][j]);
        s_x2[j] = cload(&d_h2[cur][j]);
      }
      if (iswg0) {
        float u = 0.f;
        if (tid < CD) {
          float p  = cload(&d_rec1[cur][tid]);        // OLD rec1 (for step t)
          float xv = x[(size_t)t * CD + tid];
          u = xv * logf(p) + (1.f - xv) * logf(1.f - p);
        }
        float tot = bredsum(u, s_red);
        if (tid == 0) { loss_acc += -tot; fll_acc += -tot; }
        float z = (tid < CD) ? cload(&d_z1[tid]) : -INFINITY;
        float m = bredmax(z, s_red);
        float e = (tid < CD) ? __expf(z - m) : 0.f;
        float ssum = bredsum(e, s_red);
        if (tid < CD) {
          float p = e / ssum;
          cstore(&d_rec1[nxt][tid], p);               // rec1 for step t+1
          out[2 + (size_t)t * CD + tid] = p;          // predictions[t]
        }
      }
      __syncthreads();
      for (int job = wid; job < GD; job += NWAVE) {
        const float* wr = Wih2 + (size_t)job * (2 * HD);
        float s = dotp(wr, s_x0, HD, lane)
                + dotp(wr + HD, s_x1, HD, lane)
                + dotp(Whh2 + (size_t)job * HD, s_x2, HD, lane);
        s = wredsum(s);
        if (lane == 0) cstore(&d_g2[job], s + bih2[job] + bhh2[job]);
      }
    }
    gbar(ep);

    // ---- S4: lstm2 cell ; BU2 = Ww2@TD2n ; rec2n = Vw2@h2n ----
    {
      float absum = 0.f;
      for (int j = tid; j < HD; j += NTH) {
        float gi = cload(&d_g2[j]), gf = cload(&d_g2[j + HD]);
        float gg = cload(&d_g2[j + 2 * HD]), go = cload(&d_g2[j + 3 * HD]);
        float c2n = sigf(gf) * cload(&d_c2[cur][j]) + sigf(gi) * tanhfast(gg);
        float h2n = sigf(go) * tanhfast(c2n);
        float td  = h2n - cload(&d_rec3[cur][j]);
        s_x0[j] = h2n; s_x1[j] = td;
        if (iswg0) { cstore(&d_h2[nxt][j], h2n); cstore(&d_c2[nxt][j], c2n); cstore(&d_TD2[nxt][j], td); }
        absum += fabsf(td);
      }
      if (iswg0) {
        float tot = bredsum(absum, s_red);
        if (tid == 0) loss_acc += (LAMF * LAMF) * tot;
      }
      __syncthreads();
      for (int job = wid; job < 2 * HD; job += NWAVE) {
        if (job < HD) {
          float s = dotp(Ww2 + (size_t)job * HD, s_x1, HD, lane);
          s = wredsum(s);
          if (lane == 0) cstore(&d_BU2[job], s + Wb2[job]);
        } else {
          int rr = job - HD;
          float s = dotp(Vw2 + (size_t)rr * HD, s_x0, HD, lane);
          s = wredsum(s);
          if (lane == 0) cstore(&d_rec2[nxt][rr], s + Vb2[rr]);
        }
      }
    }
    gbar(ep);

    // ---- S5: g3 = Wih3@BU2 + Whh3@h3 ; BU0(t+1) = Ww0@(x[t+1]-rec1n) ----
    {
      for (int j = tid; j < HD; j += NTH) {
        s_x0[j] = cload(&d_BU2[j]);
        s_x2[j] = cload(&d_h3[cur][j]);
      }
      if (t < TT - 1 && tid < CD)
        s_small[tid] = x[(size_t)(t + 1) * CD + tid] - cload(&d_rec1[nxt][tid]);
      __syncthreads();
      const int njob = (t < TT - 1) ? GD + HD : GD;
      for (int job = wid; job < njob; job += NWAVE) {
        if (job < GD) {
          float s = dotp(Wih3 + (size_t)job * HD, s_x0, HD, lane)
                  + dotp(Whh3 + (size_t)job * HD, s_x2, HD, lane);
          s = wredsum(s);
          if (lane == 0) cstore(&d_g3[job], s + bih3[job] + bhh3[job]);
        } else {
          int rr = job - GD;
          float s = dotp(Ww0 + (size_t)rr * CD, s_small, CD, lane);
          s = wredsum(s);
          if (lane == 0) cstore(&d_BU0[rr], s + Wb0[rr]);
        }
      }
    }
    gbar(ep);
  }

  if (iswg0 && tid == 0) { out[0] = loss_acc; out[1] = fll_acc; }
}

extern "C" void kernel_launch(void* const* d_in, const int* in_sizes, int n_in,
                              void* d_out, int out_size, void* d_ws, size_t ws_size,
                              hipStream_t stream) {
  const float* x    = (const float*)d_in[0];
  const float* Wih1 = (const float*)d_in[1];
  const float* Whh1 = (const float*)d_in[2];
  const float* bih1 = (const float*)d_in[3];
  const float* bhh1 = (const float*)d_in[4];
  const float* Vw1  = (const float*)d_in[5];
  const float* Vb1  = (const float*)d_in[6];
  const float* Wih2 = (const float*)d_in[7];
  const float* Whh2 = (const float*)d_in[8];
  const float* bih2 = (const float*)d_in[9];
  const float* bhh2 = (const float*)d_in[10];
  const float* Vw2  = (const float*)d_in[11];
  const float* Vb2  = (const float*)d_in[12];
  const float* Wih3 = (const float*)d_in[13];
  const float* Whh3 = (const float*)d_in[14];
  const float* bih3 = (const float*)d_in[15];
  const float* bhh3 = (const float*)d_in[16];
  const float* Vw3  = (const float*)d_in[17];
  const float* Vb3  = (const float*)d_in[18];
  const float* Ww0  = (const float*)d_in[19];
  const float* Wb0  = (const float*)d_in[20];
  const float* Ww1  = (const float*)d_in[21];
  const float* Wb1  = (const float*)d_in[22];
  const float* Ww2  = (const float*)d_in[23];
  const float* Wb2  = (const float*)d_in[24];
  const float* r1   = (const float*)d_in[25];
  const float* r2   = (const float*)d_in[26];
  const float* r3   = (const float*)d_in[27];

  pc_init<<<1, NWG, 0, stream>>>();
  pc_main<<<NWG, NTH, 0, stream>>>(x, Wih1, Whh1, bih1, bhh1, Vw1, Vb1,
                                   Wih2, Whh2, bih2, bhh2, Vw2, Vb2,
                                   Wih3, Whh3, bih3, bhh3, Vw3, Vb3,
                                   Ww0, Wb0, Ww1, Wb1, Ww2, Wb2,
                                   r1, r2, r3, (float*)d_out);
}